// Round 5
// baseline (234.545 us; speedup 1.0000x reference)
//
#include <hip/hip_runtime.h>
#include <hip/hip_bf16.h>
#include <math.h>

// Problem constants (fixed by reference setup_inputs)
#define BHALF 4096          // B
#define NROW 8192           // 2B
#define DIM 128             // D
#define INV_T 10.0f         // 1/temperature
#define K1 14.4269504088896f  // INV_T * log2(e): exp((v-1)*10) = exp2(v*K1 - K1)
#define LDB 136             // LDS col stride (ushorts)
#define NBLOCKS 2080        // 64 strips x 32 offsets + 32 partner tiles

typedef short bf16x8 __attribute__((ext_vector_type(8)));   // 8 bf16 = 4 VGPRs
typedef float f32x4  __attribute__((ext_vector_type(4)));   // C/D frag

// ---------------------------------------------------------------------------
// Kernel 1: row-normalize concat(view1, view2) -> e_bf16 (NROW x DIM);
// zero expsum and the completion counter. One wave per row.
// ---------------------------------------------------------------------------
__global__ __launch_bounds__(256) void normalize_kernel(
    const float* __restrict__ v1, const float* __restrict__ v2,
    __hip_bfloat16* __restrict__ e, float* __restrict__ expsum,
    unsigned int* __restrict__ counter) {
  int row  = blockIdx.x * 4 + (threadIdx.x >> 6);
  int lane = threadIdx.x & 63;
  const float* src = (row < BHALF) ? (v1 + (size_t)row * DIM)
                                   : (v2 + (size_t)(row - BHALF) * DIM);
  float2 x = ((const float2*)src)[lane];
  float ss = x.x * x.x + x.y * x.y;
#pragma unroll
  for (int off = 32; off > 0; off >>= 1) ss += __shfl_down(ss, off);
  ss = __shfl(ss, 0);
  float s = 1.0f / fmaxf(sqrtf(ss), 1e-8f);
  ((__hip_bfloat162*)(e + (size_t)row * DIM))[lane] =
      __float22bfloat162_rn(make_float2(x.x * s, x.y * s));
  if (lane == 0) expsum[row] = 0.0f;
  if (blockIdx.x == 0 && threadIdx.x == 0) *counter = 0u;
}

// ---------------------------------------------------------------------------
// Symmetric MFMA sweep over one 128x128 tile (rows: strip r, cols: strip c).
// MODE 0: diagonal tile (r==c): full tile, mask col==row, row-sums only.
// MODE 1: off-diag pair: each exp feeds row-sum AND col-sum (symmetry).
// MODE 2: partner tile (c == r^32): local-diagonal = positives, weight 2
//         (denominator col-0 term + unmasked negative), posv for BOTH rows.
// ---------------------------------------------------------------------------
template <int MODE>
__device__ __forceinline__ void sweep_tile(
    const ushort* __restrict__ Bs, const bf16x8 (&a_frag)[2][4],
    float (&rsum)[2][4], float* __restrict__ expsum,
    float* __restrict__ posv, int wave, int lane, int n, int quad,
    int rowStrip, int colStrip) {
  const int colBase = colStrip * 128;
#pragma unroll 1
  for (int sub = 0; sub < 8; ++sub) {
    const ushort* bp = &Bs[(sub * 16 + n) * LDB + quad * 8];
    bf16x8 b[4];
#pragma unroll
    for (int kk = 0; kk < 4; ++kk) b[kk] = *(const bf16x8*)(bp + kk * 32);
    float csum = 0.0f;
    const int lc = sub * 16 + n;
#pragma unroll
    for (int rf = 0; rf < 2; ++rf) {
      f32x4 acc = {0.f, 0.f, 0.f, 0.f};
#pragma unroll
      for (int kk = 0; kk < 4; ++kk)
        acc = __builtin_amdgcn_mfma_f32_16x16x32_bf16(a_frag[rf][kk], b[kk],
                                                      acc, 0, 0, 0);
      // C layout: row = quad*4 + reg, col = lane&15 (m89/m91 verified).
#pragma unroll
      for (int rr = 0; rr < 4; ++rr) {
        const int lr = wave * 32 + rf * 16 + quad * 4 + rr;
        const float val = acc[rr];
        // exp((val-1)/T) = 2^(val*K1 - K1): one v_fma + one v_exp_f32
        const float ex = __builtin_amdgcn_exp2f(val * K1 - K1);
        if (MODE == 0) {
          rsum[rf][rr] += (lr == lc) ? 0.0f : ex;       // mask true diagonal
        } else if (MODE == 1) {
          rsum[rf][rr] += ex;
          csum += ex;
        } else {                                        // partner tile
          const bool hit = (lr == lc);
          const float w = hit ? 2.0f : 1.0f;
          rsum[rf][rr] += w * ex;
          csum += w * ex;
          if (hit) {
            __hip_atomic_store(&posv[rowStrip * 128 + lr], val,
                               __ATOMIC_RELAXED, __HIP_MEMORY_SCOPE_AGENT);
            __hip_atomic_store(&posv[colBase + lc], val,
                               __ATOMIC_RELAXED, __HIP_MEMORY_SCOPE_AGENT);
          }
        }
      }
    }
    if (MODE != 0) {
      // col-sum: reduce over this wave's 32 rows (across quads), one atomic.
      csum += __shfl_xor(csum, 16);
      csum += __shfl_xor(csum, 32);
      if (lane < 16) atomicAdd(&expsum[colBase + lc], csum);
    }
  }
}

// ---------------------------------------------------------------------------
// Kernel 2: symmetric sim + online exp-sum + fused finalize (last block).
// 1D grid of 2080 blocks: bid<2048 -> (r=bid&63, d=bid>>6); else d=32,
// r=bid-2048 (r<32). col strip c=(r+d)&63. Block: 4 waves; wave w owns rows
// [r*128 + w*32, +32) with A register-resident; 128 cols staged in LDS.
// ---------------------------------------------------------------------------
__global__ __launch_bounds__(256, 4) void sim_kernel(
    const ushort* __restrict__ e, float* __restrict__ expsum,
    float* __restrict__ posv, unsigned int* __restrict__ counter,
    float* __restrict__ out) {
  int r, d;
  if (blockIdx.x < 2048) { r = blockIdx.x & 63; d = blockIdx.x >> 6; }
  else                   { r = blockIdx.x - 2048; d = 32; }
  const int c = (r + d) & 63;

  __shared__ ushort Bs[128 * LDB] __attribute__((aligned(16)));
  __shared__ float red[4];
  __shared__ int lastFlag;

  const int tid  = threadIdx.x;
  const int wave = tid >> 6;
  const int lane = tid & 63;
  const int n    = lane & 15;
  const int quad = lane >> 4;

  // Stage col strip: 128 rows of E x 256 B, coalesced uint4.
#pragma unroll
  for (int u = 0; u < 8; ++u) {
    int idx = tid + 256 * u;
    int cc  = idx >> 4;
    int q4  = idx & 15;
    *(uint4*)(&Bs[cc * LDB + q4 * 8]) =
        *(const uint4*)(e + (size_t)(c * 128 + cc) * DIM + q4 * 8);
  }

  // A fragments: 2 row-frags x 4 k-steps, register-resident.
  bf16x8 a_frag[2][4];
  const int rowWave = r * 128 + wave * 32;
#pragma unroll
  for (int rf = 0; rf < 2; ++rf) {
    const ushort* rp = e + (size_t)(rowWave + rf * 16 + n) * DIM + quad * 8;
#pragma unroll
    for (int kk = 0; kk < 4; ++kk)
      a_frag[rf][kk] = *(const bf16x8*)(rp + kk * 32);
  }

  float rsum[2][4] = {{0.f, 0.f, 0.f, 0.f}, {0.f, 0.f, 0.f, 0.f}};
  __syncthreads();

  if (d == 0)
    sweep_tile<0>(Bs, a_frag, rsum, expsum, posv, wave, lane, n, quad, r, c);
  else if (d == 32)
    sweep_tile<2>(Bs, a_frag, rsum, expsum, posv, wave, lane, n, quad, r, c);
  else
    sweep_tile<1>(Bs, a_frag, rsum, expsum, posv, wave, lane, n, quad, r, c);

  // Row sums: reduce across the 16 col-lanes, one atomic per row.
#pragma unroll
  for (int rf = 0; rf < 2; ++rf)
#pragma unroll
    for (int rr = 0; rr < 4; ++rr) {
      float v = rsum[rf][rr];
      v += __shfl_xor(v, 1);
      v += __shfl_xor(v, 2);
      v += __shfl_xor(v, 4);
      v += __shfl_xor(v, 8);
      if (n == 0) atomicAdd(&expsum[rowWave + rf * 16 + quad * 4 + rr], v);
    }

  // ---- last-block-done finalize ----
  __threadfence();          // release this block's atomics device-wide
  __syncthreads();
  if (tid == 0) {
    unsigned int old = __hip_atomic_fetch_add(counter, 1u, __ATOMIC_ACQ_REL,
                                              __HIP_MEMORY_SCOPE_AGENT);
    lastFlag = (old == NBLOCKS - 1);
  }
  __syncthreads();
  if (!lastFlag) return;
  __threadfence();          // acquire side

  float l = 0.0f;
  for (int i = tid; i < NROW; i += 256) {
    float S = __hip_atomic_load(&expsum[i], __ATOMIC_RELAXED,
                                __HIP_MEMORY_SCOPE_AGENT);
    float p = __hip_atomic_load(&posv[i], __ATOMIC_RELAXED,
                                __HIP_MEMORY_SCOPE_AGENT);
    l += __logf(S) + (1.0f - p) * INV_T;
  }
#pragma unroll
  for (int off = 32; off > 0; off >>= 1) l += __shfl_down(l, off);
  if ((tid & 63) == 0) red[tid >> 6] = l;
  __syncthreads();
  if (tid == 0) out[0] = (red[0] + red[1] + red[2] + red[3]) * (1.0f / NROW);
}

// ---------------------------------------------------------------------------
extern "C" void kernel_launch(void* const* d_in, const int* in_sizes, int n_in,
                              void* d_out, int out_size, void* d_ws, size_t ws_size,
                              hipStream_t stream) {
  const float* v1 = (const float*)d_in[0];
  const float* v2 = (const float*)d_in[1];
  float* out = (float*)d_out;

  __hip_bfloat16* e = (__hip_bfloat16*)d_ws;          // NROW*DIM bf16 (2 MB)
  float* expsum = (float*)(e + (size_t)NROW * DIM);   // NROW floats
  float* posv   = expsum + NROW;                      // NROW floats
  unsigned int* counter = (unsigned int*)(posv + NROW);

  normalize_kernel<<<NROW / 4, 256, 0, stream>>>(v1, v2, e, expsum, counter);
  sim_kernel<<<NBLOCKS, 256, 0, stream>>>((const ushort*)e, expsum, posv,
                                          counter, out);
}

// Round 6
// 81.605 us; speedup vs baseline: 2.8741x; 2.8741x over previous
//
#include <hip/hip_runtime.h>
#include <hip/hip_bf16.h>
#include <math.h>

// Problem constants (fixed by reference setup_inputs)
#define BHALF 4096          // B
#define NROW 8192           // 2B
#define DIM 128             // D
#define INV_T 10.0f         // 1/temperature
#define K1 14.4269504088896f  // INV_T*log2(e): exp((v-1)*10) = 2^(v*K1 - K1)
#define LDB 136             // LDS col stride (ushorts)

typedef short bf16x8 __attribute__((ext_vector_type(8)));   // 8 bf16 = 4 VGPRs
typedef float f32x4  __attribute__((ext_vector_type(4)));   // C/D frag

// ---------------------------------------------------------------------------
// Kernel 1: row-normalize concat(view1, view2) -> e_bf16 (NROW x DIM);
// zero expsum and d_out. One wave per row.
// ---------------------------------------------------------------------------
__global__ __launch_bounds__(256) void normalize_kernel(
    const float* __restrict__ v1, const float* __restrict__ v2,
    __hip_bfloat16* __restrict__ e, float* __restrict__ expsum,
    float* __restrict__ out) {
  int row  = blockIdx.x * 4 + (threadIdx.x >> 6);
  int lane = threadIdx.x & 63;
  const float* src = (row < BHALF) ? (v1 + (size_t)row * DIM)
                                   : (v2 + (size_t)(row - BHALF) * DIM);
  float2 x = ((const float2*)src)[lane];
  float ss = x.x * x.x + x.y * x.y;
#pragma unroll
  for (int off = 32; off > 0; off >>= 1) ss += __shfl_down(ss, off);
  ss = __shfl(ss, 0);
  float s = 1.0f / fmaxf(sqrtf(ss), 1e-8f);
  ((__hip_bfloat162*)(e + (size_t)row * DIM))[lane] =
      __float22bfloat162_rn(make_float2(x.x * s, x.y * s));
  if (lane == 0) expsum[row] = 0.0f;
  if (blockIdx.x == 0 && threadIdx.x == 0) out[0] = 0.0f;
}

// ---------------------------------------------------------------------------
// Symmetric MFMA sweep over one 128x128 tile (rows: strip r, cols: strip c).
// MODE 0: diagonal tile (r==c): full tile, mask col==row, row-sums only.
// MODE 1: off-diag pair: each exp feeds row-sum AND col-sum (symmetry).
// MODE 2: partner tile (c == r^32): local-diagonal = positives, weight 2
//         (denominator col-0 term + unmasked negative), posv for BOTH rows.
// NOTE: no per-block device fences anywhere — R5 showed a per-block
// __threadfence costs ~80 ns serialized at TCC (2080 blocks -> +150 us).
// ---------------------------------------------------------------------------
template <int MODE>
__device__ __forceinline__ void sweep_tile(
    const ushort* __restrict__ Bs, const bf16x8 (&a_frag)[2][4],
    float (&rsum)[2][4], float* __restrict__ expsum,
    float* __restrict__ posv, int wave, int lane, int n, int quad,
    int rowStrip, int colStrip) {
  const int colBase = colStrip * 128;
#pragma unroll 1
  for (int sub = 0; sub < 8; ++sub) {
    const ushort* bp = &Bs[(sub * 16 + n) * LDB + quad * 8];
    bf16x8 b[4];
#pragma unroll
    for (int kk = 0; kk < 4; ++kk) b[kk] = *(const bf16x8*)(bp + kk * 32);
    float csum = 0.0f;
    const int lc = sub * 16 + n;
#pragma unroll
    for (int rf = 0; rf < 2; ++rf) {
      f32x4 acc = {0.f, 0.f, 0.f, 0.f};
#pragma unroll
      for (int kk = 0; kk < 4; ++kk)
        acc = __builtin_amdgcn_mfma_f32_16x16x32_bf16(a_frag[rf][kk], b[kk],
                                                      acc, 0, 0, 0);
      // C layout: row = quad*4 + reg, col = lane&15 (m89/m91 verified).
#pragma unroll
      for (int rr = 0; rr < 4; ++rr) {
        const int lr = wave * 32 + rf * 16 + quad * 4 + rr;
        const float val = acc[rr];
        // exp((val-1)/T) = 2^(val*K1 - K1): one v_fma + one v_exp_f32
        const float ex = __builtin_amdgcn_exp2f(val * K1 - K1);
        if (MODE == 0) {
          rsum[rf][rr] += (lr == lc) ? 0.0f : ex;       // mask true diagonal
        } else if (MODE == 1) {
          rsum[rf][rr] += ex;
          csum += ex;
        } else {                                        // partner tile
          const bool hit = (lr == lc);
          const float w = hit ? 2.0f : 1.0f;
          rsum[rf][rr] += w * ex;
          csum += w * ex;
          if (hit) {
            posv[rowStrip * 128 + lr] = val;            // row i
            posv[colBase + lc] = val;                   // partner j = i^4096
          }
        }
      }
    }
    if (MODE != 0) {
      // col-sum: reduce over this wave's 32 rows (across quads), one atomic.
      csum += __shfl_xor(csum, 16);
      csum += __shfl_xor(csum, 32);
      if (lane < 16) atomicAdd(&expsum[colBase + lc], csum);
    }
  }
}

// ---------------------------------------------------------------------------
// Kernel 2: symmetric sim + online exp-sum. Grid (64, 33): x = row strip,
// y = cyclic offset d; col strip = (r+d)&63. d=32 valid only for r<32.
// Block: 4 waves; wave w owns rows [r*128 + w*32, +32) with A register-
// resident; 128 cols of strip c staged once in LDS (shared by 4 waves).
// ---------------------------------------------------------------------------
__global__ __launch_bounds__(256, 4) void sim_kernel(
    const ushort* __restrict__ e, float* __restrict__ expsum,
    float* __restrict__ posv) {
  const int r = blockIdx.x;
  const int d = blockIdx.y;
  if (d == 32 && r >= 32) return;   // uniform: whole block exits, no barrier hazard
  const int c = (r + d) & 63;

  __shared__ ushort Bs[128 * LDB] __attribute__((aligned(16)));

  const int tid  = threadIdx.x;
  const int wave = tid >> 6;
  const int lane = tid & 63;
  const int n    = lane & 15;
  const int quad = lane >> 4;

  // Stage col strip: 128 rows of E x 256 B, coalesced uint4.
#pragma unroll
  for (int u = 0; u < 8; ++u) {
    int idx = tid + 256 * u;
    int cc  = idx >> 4;
    int q4  = idx & 15;
    *(uint4*)(&Bs[cc * LDB + q4 * 8]) =
        *(const uint4*)(e + (size_t)(c * 128 + cc) * DIM + q4 * 8);
  }

  // A fragments: 2 row-frags x 4 k-steps, register-resident.
  bf16x8 a_frag[2][4];
  const int rowWave = r * 128 + wave * 32;
#pragma unroll
  for (int rf = 0; rf < 2; ++rf) {
    const ushort* rp = e + (size_t)(rowWave + rf * 16 + n) * DIM + quad * 8;
#pragma unroll
    for (int kk = 0; kk < 4; ++kk)
      a_frag[rf][kk] = *(const bf16x8*)(rp + kk * 32);
  }

  float rsum[2][4] = {{0.f, 0.f, 0.f, 0.f}, {0.f, 0.f, 0.f, 0.f}};
  __syncthreads();

  if (d == 0)
    sweep_tile<0>(Bs, a_frag, rsum, expsum, posv, wave, lane, n, quad, r, c);
  else if (d == 32)
    sweep_tile<2>(Bs, a_frag, rsum, expsum, posv, wave, lane, n, quad, r, c);
  else
    sweep_tile<1>(Bs, a_frag, rsum, expsum, posv, wave, lane, n, quad, r, c);

  // Row sums: reduce across the 16 col-lanes, one atomic per row.
#pragma unroll
  for (int rf = 0; rf < 2; ++rf)
#pragma unroll
    for (int rr = 0; rr < 4; ++rr) {
      float v = rsum[rf][rr];
      v += __shfl_xor(v, 1);
      v += __shfl_xor(v, 2);
      v += __shfl_xor(v, 4);
      v += __shfl_xor(v, 8);
      if (n == 0) atomicAdd(&expsum[rowWave + rf * 16 + quad * 4 + rr], v);
    }
}

// ---------------------------------------------------------------------------
// Kernel 3: loss_i = log(S_i) + (1 - pos_i)/T ; out = mean (atomic partials).
// 32 blocks x 256 threads, one row per thread.
// ---------------------------------------------------------------------------
__global__ __launch_bounds__(256) void finalize_kernel(
    const float* __restrict__ expsum, const float* __restrict__ posv,
    float* __restrict__ out) {
  __shared__ float red[4];
  const int i = blockIdx.x * 256 + threadIdx.x;
  float l = __logf(expsum[i]) + (1.0f - posv[i]) * INV_T;
#pragma unroll
  for (int off = 32; off > 0; off >>= 1) l += __shfl_down(l, off);
  if ((threadIdx.x & 63) == 0) red[threadIdx.x >> 6] = l;
  __syncthreads();
  if (threadIdx.x == 0)
    atomicAdd(out, (red[0] + red[1] + red[2] + red[3]) * (1.0f / NROW));
}

// ---------------------------------------------------------------------------
extern "C" void kernel_launch(void* const* d_in, const int* in_sizes, int n_in,
                              void* d_out, int out_size, void* d_ws, size_t ws_size,
                              hipStream_t stream) {
  const float* v1 = (const float*)d_in[0];
  const float* v2 = (const float*)d_in[1];
  float* out = (float*)d_out;

  __hip_bfloat16* e = (__hip_bfloat16*)d_ws;          // NROW*DIM bf16 (2 MB)
  float* expsum = (float*)(e + (size_t)NROW * DIM);   // NROW floats
  float* posv   = expsum + NROW;                      // NROW floats

  normalize_kernel<<<NROW / 4, 256, 0, stream>>>(v1, v2, e, expsum, out);
  dim3 grid(64, 33);
  sim_kernel<<<grid, 256, 0, stream>>>((const ushort*)e, expsum, posv);
  finalize_kernel<<<32, 256, 0, stream>>>(expsum, posv, out);
}